// Round 7
// baseline (281.735 us; speedup 1.0000x reference)
//
#include <hip/hip_runtime.h>
#include <math.h>

// z:  (2,1,256,256,64)  idx = b*4194304 + x*16384 + y*64 + k
// tg: (2,3,256,256,64)  idx = b*12582912 + c*4194304 + x*16384 + y*64 + k
//
// Tiled stencil: block = 4x4 cells, full k (64). z AND b staged in LDS
// (rounds 1-3 proved global-sourced operands held across the barrier spill
// to scratch; rounds 0/4 proved LDS-sourced ones don't).
//
// This round: compute phase uses NAMED float4 fragments + __shfl tails +
// constant-folding selectors (round 3's proven-correct expressions), sourced
// from LDS after the barrier. This pins fragments in registers: round 4's
// VGPR_Count=64 showed the compiler was lazily re-reading LDS per operand
// use (scalar ds_read + address VALU each time) instead of keeping values
// live. One ds_read_b128 per fragment (18/thread total), zero scalar reads.
//
// Shfl tails are computed unconditionally (outside divergent guards); the
// lane-edge garbage (kq==15 / kq==0 / cross-cell) is masked by the k-range
// guards -- verified absmax==0 in rounds 2-3.
//
// ws layout (floats), 32 slices x 258:
//   sl[p*258 + 0]=smooth, +1=div, +2+b*64+k = s1, +130+b*64+k = s2

#define ZSTR 388            // 6*64 + 4 pad
#define BSTR 324            // 5*64 + 4 pad
#define BFLD 1620           // 5*BSTR

__global__ __launch_bounds__(512) void zero_ws_kernel(float* ws) {
    for (int i = threadIdx.x; i < 32 * 258; i += 512) ws[i] = 0.0f;
}

// constant-folding 5-element selector: v.x..v.w for i=0..3, tail t for i=4
#define EL5(v, t, i) \
    ((i) == 0 ? (v).x : (i) == 1 ? (v).y : (i) == 2 ? (v).z : (i) == 3 ? (v).w : (t))

__global__ __launch_bounds__(256, 4) void fused_loss_kernel(
    const float* __restrict__ zin, const float* __restrict__ tg,
    float* __restrict__ ws)
{
    __shared__ float zs[6 * ZSTR];       // 2328 floats
    __shared__ float bs[3 * BFLD];       // 4860 floats
    __shared__ float rsc[4][2];

    const int tid  = threadIdx.x;
    const int lane = tid & 63;
    const int w    = tid >> 6;

    const int bb = blockIdx.x >> 12;
    const int rest = blockIdx.x & 4095;
    const int x0 = ((rest >> 6) & 63) << 2;
    const int y0 = (rest & 63) << 2;

    const float* zg = zin + ((size_t)bb << 22);

    // ---- cooperative staging: 576 z float4s + 1200 b float4s ----
    for (int i = tid; i < 1776; i += 256) {
        if (i < 576) {
            int row = i >> 4;
            int o   = (i & 15) << 2;
            int xi  = row / 6;
            int yr  = row - xi * 6;
            int x = x0 - 1 + xi; x = x < 0 ? 0 : (x > 255 ? 255 : x);
            int y = y0 - 1 + yr; y = y < 0 ? 0 : (y > 255 ? 255 : y);
            *(float4*)&zs[xi * ZSTR + yr * 64 + o] =
                *(const float4*)&zg[x * 16384 + y * 64 + o];
        } else {
            int j  = i - 576;
            int f  = j / 400;
            int jj = j - f * 400;
            int row = jj >> 4;
            int o   = (jj & 15) << 2;
            int xi  = row / 5;
            int yr  = row - xi * 5;
            int x = x0 + xi; x = x > 255 ? 255 : x;
            int y = y0 + yr; y = y > 255 ? 255 : y;
            const float* g = tg + ((size_t)(bb * 3 + f) << 22);
            *(float4*)&bs[f * BFLD + xi * BSTR + yr * 64 + o] =
                *(const float4*)&g[x * 16384 + y * 64 + o];
        }
    }
    __syncthreads();

    // ---- compute: thread = (cell, k-quad) ----
    const int c  = tid >> 4;
    const int kq = tid & 15;
    const int cx = c & 3, cy = c >> 2;
    const int xg = x0 + cx, yg = y0 + cy;
    const int k0 = kq << 2;

    // z fragments: one ds_read_b128 each
    const float* zC = &zs[(cx + 1) * ZSTR + (cy + 1) * 64 + k0];
    float4 za   = *(const float4*)(zC);
    float4 zE4  = *(const float4*)(zC + ZSTR);
    float4 zW4  = *(const float4*)(zC - ZSTR);
    float4 zN4  = *(const float4*)(zC + 64);
    float4 zS4  = *(const float4*)(zC - 64);
    float4 zNE4 = *(const float4*)(zC + ZSTR + 64);

    // b fragments: one ds_read_b128 each, UNCONDITIONAL (needed so the shfl
    // tails below are wave-complete; staged values are always valid).
    const float* bxP = &bs[cx * BSTR + cy * 64 + k0];
    const float* byP = bxP + BFLD;
    const float* bzP = byP + BFLD;
    float4 bx00 = *(const float4*)(bxP);
    float4 bx10 = *(const float4*)(bxP + BSTR);
    float4 bx01 = *(const float4*)(bxP + 64);
    float4 bx11 = *(const float4*)(bxP + BSTR + 64);
    float4 by00 = *(const float4*)(byP);
    float4 by10 = *(const float4*)(byP + BSTR);
    float4 by01 = *(const float4*)(byP + 64);
    float4 by11 = *(const float4*)(byP + BSTR + 64);
    float4 bz00 = *(const float4*)(bzP);
    float4 bz10 = *(const float4*)(bzP + BSTR);
    float4 bz01 = *(const float4*)(bzP + 64);
    float4 bz11 = *(const float4*)(bzP + BSTR + 64);

    // cross-lane tails (unconditional; lane-edge garbage masked by k guards)
    float zcm1 = __shfl_up(za.w, 1, 64);       // z[k0-1]; kq==0 -> masked (k=0)
    float zp4  = __shfl_down(za.x, 1, 64);     // z[k0+4]; kq==15 -> masked
    float zp5  = __shfl_down(za.y, 1, 64);     // z[k0+5]; kq==15 -> masked
    float zEt  = __shfl_down(zE4.x,  1, 64);
    float zWt  = __shfl_down(zW4.x,  1, 64);
    float zNt  = __shfl_down(zN4.x,  1, 64);
    float zSt  = __shfl_down(zS4.x,  1, 64);
    float zNEt = __shfl_down(zNE4.x, 1, 64);

    float bx00t = __shfl_down(bx00.x, 1, 64);
    float bx10t = __shfl_down(bx10.x, 1, 64);
    float bx01t = __shfl_down(bx01.x, 1, 64);
    float bx11t = __shfl_down(bx11.x, 1, 64);
    float by00t = __shfl_down(by00.x, 1, 64);
    float by10t = __shfl_down(by10.x, 1, 64);
    float by01t = __shfl_down(by01.x, 1, 64);
    float by11t = __shfl_down(by11.x, 1, 64);
    float bz00t = __shfl_down(bz00.x, 1, 64);
    float bz10t = __shfl_down(bz10.x, 1, 64);
    float bz01t = __shfl_down(bz01.x, 1, 64);
    float bz11t = __shfl_down(bz11.x, 1, 64);

    // selectors (indices become literals after #pragma unroll)
    #define ZC7(i) ((i) == 0 ? zcm1 : (i) == 1 ? za.x : (i) == 2 ? za.y : \
                    (i) == 3 ? za.z : (i) == 4 ? za.w : (i) == 5 ? zp4 : zp5)
    #define ZE(i)   EL5(zE4,  zEt,  i)
    #define ZW(i)   EL5(zW4,  zWt,  i)
    #define ZN(i)   EL5(zN4,  zNt,  i)
    #define ZS(i)   EL5(zS4,  zSt,  i)
    #define ZNE(i)  EL5(zNE4, zNEt, i)
    #define BX00(i) EL5(bx00, bx00t, i)
    #define BX10(i) EL5(bx10, bx10t, i)
    #define BX01(i) EL5(bx01, bx01t, i)
    #define BX11(i) EL5(bx11, bx11t, i)
    #define BY00(i) EL5(by00, by00t, i)
    #define BY10(i) EL5(by10, by10t, i)
    #define BY01(i) EL5(by01, by01t, i)
    #define BY11(i) EL5(by11, by11t, i)
    #define BZ00(i) EL5(bz00, bz00t, i)
    #define BZ10(i) EL5(bz10, bz10t, i)
    #define BZ01(i) EL5(bz01, bz01t, i)
    #define BZ11(i) EL5(bz11, bz11t, i)

    // smooth
    float sm = 0.0f;
    if (xg >= 1 && xg <= 254 && yg >= 1 && yg <= 254) {
        #pragma unroll
        for (int e = 0; e < 4; ++e) {
            int k = k0 + e;
            if (k >= 1 && k <= 61) {
                float dz0e = ZC7(e + 2) - ZC7(e + 1);
                float dzm  = ZC7(e + 1) - ZC7(e);
                float dzp  = ZC7(e + 3) - ZC7(e + 2);
                float dzw  = ZW(e + 1) - ZW(e);
                float dzs  = ZS(e + 1) - ZS(e);
                float dze  = ZE(e + 1) - ZE(e);
                float dzn  = ZN(e + 1) - ZN(e);
                float lap = 6.0f * dz0e * dz0e
                          - dzw * dzw - dze * dze
                          - dzs * dzs - dzn * dzn
                          - dzm * dzm - dzp * dzp;
                sm += lap * lap;
            }
        }
    }

    // div
    float dv = 0.0f;
    if (xg < 255 && yg < 255) {
        const float c6 = 1.0f / 6.0f;
        #pragma unroll
        for (int e = 0; e < 4; ++e) {
            if ((k0 + e) < 63) {
                float dz0e  = ZC7(e + 2) - ZC7(e + 1);
                float dzEe  = ZE(e + 1) - ZE(e);
                float dzNe  = ZN(e + 1) - ZN(e);
                float dzNEe = ZNE(e + 1) - ZNE(e);
                float adz00 = fabsf(dz0e),  adz10 = fabsf(dzEe);
                float adz01 = fabsf(dzNe),  adz11 = fabsf(dzNEe);

                float num =
                    0.125f * ( (BX10(e) + BX10(e+1) + BX11(e) + BX11(e+1)) * (adz10 + adz11)
                             - (BX00(e) + BX00(e+1) + BX01(e) + BX01(e+1)) * (adz00 + adz01)
                             + (BY01(e) + BY01(e+1) + BY11(e) + BY11(e+1)) * (adz01 + adz11)
                             - (BY00(e) + BY00(e+1) + BY10(e) + BY10(e+1)) * (adz00 + adz10) )
                  + 0.25f * ( (BZ00(e+1) + BZ10(e+1) + BZ01(e+1) + BZ11(e+1))
                            - (BZ00(e)   + BZ10(e)   + BZ01(e)   + BZ11(e)) );

                num += c6 * ( (BX00(e+1) + BX10(e+1) + BX11(e+1)) * (ZC7(e+2) - ZE(e+1))
                            + (BX01(e+1) + BX11(e+1) + BX10(e+1)) * (ZN(e+1) - ZNE(e+1))
                            + (BY10(e+1) + BY11(e+1) + BY01(e+1)) * (ZE(e+1) - ZNE(e+1))
                            + (BY00(e+1) + BY01(e+1) + BY11(e+1)) * (ZC7(e+2) - ZN(e+1))
                            - (BX00(e) + BX10(e) + BX11(e)) * (ZC7(e+1) - ZE(e))
                            - (BX01(e) + BX11(e) + BX10(e)) * (ZN(e) - ZNE(e))
                            - (BY10(e) + BY11(e) + BY01(e)) * (ZE(e) - ZNE(e))
                            - (BY00(e) + BY01(e) + BY11(e)) * (ZC7(e+1) - ZN(e)) );

                float sbx = BX00(e) + BX00(e+1) + BX10(e) + BX10(e+1)
                          + BX01(e) + BX01(e+1) + BX11(e) + BX11(e+1);
                float sby = BY00(e) + BY00(e+1) + BY10(e) + BY10(e+1)
                          + BY01(e) + BY01(e+1) + BY11(e) + BY11(e+1);
                float sbz = BZ00(e) + BZ00(e+1) + BZ10(e) + BZ10(e+1)
                          + BZ01(e) + BZ01(e+1) + BZ11(e) + BZ11(e+1);
                float den = 0.015625f * (sbx * sbx + sby * sby + sbz * sbz) + 1e-10f;
                dv += num * num / den;
            }
        }
    }

    // ---- block reduction ----
    #pragma unroll
    for (int off = 32; off > 0; off >>= 1) {
        sm += __shfl_down(sm, off, 64);
        dv += __shfl_down(dv, off, 64);
    }

    __syncthreads();   // all LDS reads done; safe to reuse zs
    float* r1 = zs;            // 1024 floats
    float* r2 = zs + 1024;     // 1024 floats
    {
        // std partials computed at write time (k<63 valid)
        float4 v1, v2;
        float d;
        d = (k0 + 0) < 63 ? (ZC7(2) - ZC7(1)) : 0.0f; v1.x = d; v2.x = d * d;
        d = (k0 + 1) < 63 ? (ZC7(3) - ZC7(2)) : 0.0f; v1.y = d; v2.y = d * d;
        d = (k0 + 2) < 63 ? (ZC7(4) - ZC7(3)) : 0.0f; v1.z = d; v2.z = d * d;
        d = (k0 + 3) < 63 ? (ZC7(5) - ZC7(4)) : 0.0f; v1.w = d; v2.w = d * d;
        *(float4*)&r1[tid << 2] = v1;
        *(float4*)&r2[tid << 2] = v2;
    }
    if (lane == 0) { rsc[w][0] = sm; rsc[w][1] = dv; }
    __syncthreads();

    if (tid < 64) {
        float a = 0.0f, b2r = 0.0f;
        #pragma unroll
        for (int cc = 0; cc < 16; ++cc) {
            a   += r1[cc * 64 + tid];
            b2r += r2[cc * 64 + tid];
        }
        float* sl = ws + (blockIdx.x & 31) * 258;
        if (tid < 63) {
            atomicAdd(&sl[2 + bb * 64 + tid],   a);
            atomicAdd(&sl[130 + bb * 64 + tid], b2r);
        }
        if (tid == 0) atomicAdd(&sl[0], rsc[0][0] + rsc[1][0] + rsc[2][0] + rsc[3][0]);
        if (tid == 1) atomicAdd(&sl[1], rsc[0][1] + rsc[1][1] + rsc[2][1] + rsc[3][1]);
    }
}

__global__ __launch_bounds__(128) void finalize_kernel(const float* __restrict__ ws,
                                                       float* __restrict__ out)
{
    __shared__ double red[128];
    const int t = threadIdx.x;
    double stdv = 0.0;
    {
        int k = t & 63, bb = t >> 6;
        if (k < 63) {
            double s1 = 0.0, s2 = 0.0;
            for (int p = 0; p < 32; ++p) {
                s1 += (double)ws[p * 258 + 2 + bb * 64 + k];
                s2 += (double)ws[p * 258 + 130 + bb * 64 + k];
            }
            const double N = 65536.0;
            double var = (s2 - s1 * s1 / N) / (N - 1.0);
            stdv = sqrt(var > 0.0 ? var : 0.0);
        }
    }
    red[t] = stdv;
    __syncthreads();
    for (int off = 64; off > 0; off >>= 1) {
        if (t < off) red[t] += red[t + off];
        __syncthreads();
    }
    if (t == 0) {
        double smt = 0.0, dvt = 0.0;
        for (int p = 0; p < 32; ++p) {
            smt += (double)ws[p * 258 + 0];
            dvt += (double)ws[p * 258 + 1];
        }
        double loss_std    = red[0] / 126.0;
        double loss_smooth = smt / (2.0 * 254.0 * 254.0 * 61.0);
        double loss_div    = dvt / (2.0 * 255.0 * 255.0 * 63.0);
        out[0] = (float)(loss_div * 1e9);
        out[1] = (float)(loss_smooth * 10.0 + loss_std * 100.0);
    }
}

extern "C" void kernel_launch(void* const* d_in, const int* in_sizes, int n_in,
                              void* d_out, int out_size, void* d_ws, size_t ws_size,
                              hipStream_t stream) {
    const float* z  = (const float*)d_in[0];   // outputs (2,1,256,256,64)
    const float* tg = (const float*)d_in[1];   // targets (2,3,256,256,64)
    float* out = (float*)d_out;
    float* ws  = (float*)d_ws;

    zero_ws_kernel<<<1, 512, 0, stream>>>(ws);
    // 64x64 tiles x 2 batches = 8192 blocks
    fused_loss_kernel<<<8192, 256, 0, stream>>>(z, tg, ws);
    finalize_kernel<<<1, 128, 0, stream>>>(ws, out);
}

// Round 8
// 202.209 us; speedup vs baseline: 1.3933x; 1.3933x over previous
//
#include <hip/hip_runtime.h>
#include <math.h>

// z:  (2,1,256,256,64)  idx = b*4194304 + x*16384 + y*64 + k
// tg: (2,3,256,256,64)  idx = b*12582912 + c*4194304 + x*16384 + y*64 + k
//
// REMAPPED: wave = one (x,y) cell, lane = k (k is the contiguous 64-wide axis).
// - every z/b row is ONE coalesced 256B global dword load per wave (no LDS
//   staging at all; L1/L2 serve the 4-6x halo reuse between neighbor cells)
// - k-neighbors come from __shfl (bitwise-identical to the old array reads:
//   dzm/dzp are the neighbor lane's own subtraction)
// - straight-line scalar code: no arrays (rounds 1-3: allocas -> scratch),
//   no cross-barrier float4 banks (rounds 5/7: >60 live floats -> the
//   allocator pins 64 VGPRs and spills). Peak live here ~55 floats.
// - x/y guards are wave-uniform; lane guards (k<63 etc.) contain no shfls.
// Block = 4 waves = 2x2 cells. Grid = 2 batches x 128x128 tiles = 32768.
//
// ws layout (floats), 32 slices x 258:
//   sl[p*258 + 0]=smooth, +1=div, +2+b*64+k = s1, +130+b*64+k = s2

__global__ __launch_bounds__(512) void zero_ws_kernel(float* ws) {
    for (int i = threadIdx.x; i < 32 * 258; i += 512) ws[i] = 0.0f;
}

__global__ __launch_bounds__(256, 4) void fused_loss_kernel(
    const float* __restrict__ zin, const float* __restrict__ tg,
    float* __restrict__ ws)
{
    __shared__ float r1[4][64];
    __shared__ float r2[4][64];
    __shared__ float rsc[4][2];

    const int tid  = threadIdx.x;
    const int lane = tid & 63;
    const int w    = tid >> 6;

    // blockIdx = bb*16384 + ty*128 + tx ; wave w -> cell (2tx + (w>>1), 2ty + (w&1))
    const int bb   = blockIdx.x >> 14;
    const int rest = blockIdx.x & 16383;
    const int tx   = rest & 127;
    const int ty   = rest >> 7;
    const int x    = (tx << 1) | (w >> 1);
    const int y    = (ty << 1) | (w & 1);

    const float* zb = zin + ((size_t)bb << 22);
    const int xp = x < 255 ? x + 1 : 255;
    const int yp = y < 255 ? y + 1 : 255;

    // z rows: one coalesced dword load per wave each
    float zC  = zb[x  * 16384 + y  * 64 + lane];
    float zE  = zb[xp * 16384 + y  * 64 + lane];
    float zN  = zb[x  * 16384 + yp * 64 + lane];
    float zNE = zb[xp * 16384 + yp * 64 + lane];

    float zCp  = __shfl_down(zC,  1, 64);   // z[k+1]; lane63 garbage (masked k<63)
    float zEp  = __shfl_down(zE,  1, 64);
    float zNp  = __shfl_down(zN,  1, 64);
    float zNEp = __shfl_down(zNE, 1, 64);

    float dz   = zCp  - zC;                 // dz[k], valid k<63
    float dzE  = zEp  - zE;
    float dzN  = zNp  - zN;
    float dzNE = zNEp - zNE;

    // std partials (k<63 valid) -- covers ALL x,y 0..255
    float s1 = (lane < 63) ? dz : 0.0f;
    float s2 = (lane < 63) ? dz * dz : 0.0f;

    // ---- smooth (wave-uniform xy guard; shfls before the lane guard) ----
    float sm = 0.0f;
    if (x >= 1 && x <= 254 && y >= 1 && y <= 254) {
        float zW  = zb[(x - 1) * 16384 + y * 64 + lane];
        float zS  = zb[x * 16384 + (y - 1) * 64 + lane];
        float zWp = __shfl_down(zW, 1, 64);
        float zSp = __shfl_down(zS, 1, 64);
        float dzW = zWp - zW;
        float dzS = zSp - zS;
        float dzm = __shfl_up(dz, 1, 64);    // dz[k-1]; lane0 garbage (masked k>=1)
        float dzp = __shfl_down(dz, 1, 64);  // dz[k+1]; valid through k=61
        if (lane >= 1 && lane <= 61) {
            float lap = 6.0f * dz * dz
                      - dzW * dzW - dzE * dzE
                      - dzS * dzS - dzN * dzN
                      - dzm * dzm - dzp * dzp;
            sm = lap * lap;
        }
    }

    // ---- div (wave-uniform xy guard; b loads+shfls at point of use) ----
    float dv = 0.0f;
    if (x < 255 && y < 255) {
        const float* bB = tg + (((size_t)bb * 3) << 22) + x * 16384 + y * 64 + lane;
        float bx00 = bB[0];
        float bx10 = bB[16384];
        float bx01 = bB[64];
        float bx11 = bB[16448];
        const float* bY = bB + 4194304;
        float by00 = bY[0];
        float by10 = bY[16384];
        float by01 = bY[64];
        float by11 = bY[16448];
        const float* bZ = bB + 8388608;
        float bz00 = bZ[0];
        float bz10 = bZ[16384];
        float bz01 = bZ[64];
        float bz11 = bZ[16448];

        float bx00p = __shfl_down(bx00, 1, 64);
        float bx10p = __shfl_down(bx10, 1, 64);
        float bx01p = __shfl_down(bx01, 1, 64);
        float bx11p = __shfl_down(bx11, 1, 64);
        float by00p = __shfl_down(by00, 1, 64);
        float by10p = __shfl_down(by10, 1, 64);
        float by01p = __shfl_down(by01, 1, 64);
        float by11p = __shfl_down(by11, 1, 64);
        float bz00p = __shfl_down(bz00, 1, 64);
        float bz10p = __shfl_down(bz10, 1, 64);
        float bz01p = __shfl_down(bz01, 1, 64);
        float bz11p = __shfl_down(bz11, 1, 64);

        if (lane < 63) {
            float adz00 = fabsf(dz),  adz10 = fabsf(dzE);
            float adz01 = fabsf(dzN), adz11 = fabsf(dzNE);

            float num =
                0.125f * ( (bx10 + bx10p + bx11 + bx11p) * (adz10 + adz11)
                         - (bx00 + bx00p + bx01 + bx01p) * (adz00 + adz01)
                         + (by01 + by01p + by11 + by11p) * (adz01 + adz11)
                         - (by00 + by00p + by10 + by10p) * (adz00 + adz10) )
              + 0.25f * ( (bz00p + bz10p + bz01p + bz11p)
                        - (bz00  + bz10  + bz01  + bz11) );

            const float c6 = 1.0f / 6.0f;
            num += c6 * ( (bx00p + bx10p + bx11p) * (zCp - zEp)
                        + (bx01p + bx11p + bx10p) * (zNp - zNEp)
                        + (by10p + by11p + by01p) * (zEp - zNEp)
                        + (by00p + by01p + by11p) * (zCp - zNp)
                        - (bx00 + bx10 + bx11) * (zC - zE)
                        - (bx01 + bx11 + bx10) * (zN - zNE)
                        - (by10 + by11 + by01) * (zE - zNE)
                        - (by00 + by01 + by11) * (zC - zN) );

            float sbx = bx00 + bx00p + bx10 + bx10p
                      + bx01 + bx01p + bx11 + bx11p;
            float sby = by00 + by00p + by10 + by10p
                      + by01 + by01p + by11 + by11p;
            float sbz = bz00 + bz00p + bz10 + bz10p
                      + bz01 + bz01p + bz11 + bz11p;
            float den = 0.015625f * (sbx * sbx + sby * sby + sbz * sbz) + 1e-10f;
            dv = num * num / den;
        }
    }

    // ---- reductions ----
    #pragma unroll
    for (int off = 32; off > 0; off >>= 1) {
        sm += __shfl_down(sm, off, 64);
        dv += __shfl_down(dv, off, 64);
    }
    r1[w][lane] = s1;
    r2[w][lane] = s2;
    if (lane == 0) { rsc[w][0] = sm; rsc[w][1] = dv; }
    __syncthreads();

    if (tid < 64) {
        float a   = r1[0][tid] + r1[1][tid] + r1[2][tid] + r1[3][tid];
        float b2r = r2[0][tid] + r2[1][tid] + r2[2][tid] + r2[3][tid];
        float* sl = ws + (blockIdx.x & 31) * 258;
        if (tid < 63) {
            atomicAdd(&sl[2 + bb * 64 + tid],   a);
            atomicAdd(&sl[130 + bb * 64 + tid], b2r);
        }
        if (tid == 0) atomicAdd(&sl[0], rsc[0][0] + rsc[1][0] + rsc[2][0] + rsc[3][0]);
        if (tid == 1) atomicAdd(&sl[1], rsc[0][1] + rsc[1][1] + rsc[2][1] + rsc[3][1]);
    }
}

__global__ __launch_bounds__(128) void finalize_kernel(const float* __restrict__ ws,
                                                       float* __restrict__ out)
{
    __shared__ double red[128];
    const int t = threadIdx.x;
    double stdv = 0.0;
    {
        int k = t & 63, bb = t >> 6;
        if (k < 63) {
            double s1 = 0.0, s2 = 0.0;
            for (int p = 0; p < 32; ++p) {
                s1 += (double)ws[p * 258 + 2 + bb * 64 + k];
                s2 += (double)ws[p * 258 + 130 + bb * 64 + k];
            }
            const double N = 65536.0;
            double var = (s2 - s1 * s1 / N) / (N - 1.0);
            stdv = sqrt(var > 0.0 ? var : 0.0);
        }
    }
    red[t] = stdv;
    __syncthreads();
    for (int off = 64; off > 0; off >>= 1) {
        if (t < off) red[t] += red[t + off];
        __syncthreads();
    }
    if (t == 0) {
        double smt = 0.0, dvt = 0.0;
        for (int p = 0; p < 32; ++p) {
            smt += (double)ws[p * 258 + 0];
            dvt += (double)ws[p * 258 + 1];
        }
        double loss_std    = red[0] / 126.0;
        double loss_smooth = smt / (2.0 * 254.0 * 254.0 * 61.0);
        double loss_div    = dvt / (2.0 * 255.0 * 255.0 * 63.0);
        out[0] = (float)(loss_div * 1e9);
        out[1] = (float)(loss_smooth * 10.0 + loss_std * 100.0);
    }
}

extern "C" void kernel_launch(void* const* d_in, const int* in_sizes, int n_in,
                              void* d_out, int out_size, void* d_ws, size_t ws_size,
                              hipStream_t stream) {
    const float* z  = (const float*)d_in[0];   // outputs (2,1,256,256,64)
    const float* tg = (const float*)d_in[1];   // targets (2,3,256,256,64)
    float* out = (float*)d_out;
    float* ws  = (float*)d_ws;

    zero_ws_kernel<<<1, 512, 0, stream>>>(ws);
    // 2 batches x 128x128 tiles of 2x2 cells = 32768 blocks
    fused_loss_kernel<<<32768, 256, 0, stream>>>(z, tg, ws);
    finalize_kernel<<<1, 128, 0, stream>>>(ws, out);
}